// Round 7
// baseline (147.239 us; speedup 1.0000x reference)
//
#include <hip/hip_runtime.h>

typedef unsigned short u16;
typedef unsigned int u32;

typedef __bf16 bf16x8 __attribute__((ext_vector_type(8)));
typedef float floatx4 __attribute__((ext_vector_type(4)));

// ---- helpers ----------------------------------------------------------------

__device__ __forceinline__ u32 f2bf(float f) {
    // round-to-nearest-even fp32 -> bf16 (bit pattern in low 16)
    u32 u = __builtin_bit_cast(u32, f);
    return (u + 0x7fffu + ((u >> 16) & 1u)) >> 16;
}

__device__ __forceinline__ float quant_w(float x) {
    // WAGE Quantize.W, BITS_W=2: clip to [-0.5,0.5], round to grid step 0.5 (RNE)
    float xc = fminf(fmaxf(x, -0.5f), 0.5f);
    return rintf(xc * 2.0f) * 0.5f;
}

__device__ __forceinline__ void gload_lds16(const u16* g, u16* l) {
    __builtin_amdgcn_global_load_lds(
        (const __attribute__((address_space(1))) void*)g,
        (__attribute__((address_space(3))) void*)l,
        16, 0, 0);
}

// ---- kernel 1: cast A fp32 -> bf16 (16 floats / thread) ---------------------

__global__ __launch_bounds__(256) void cast_a_kernel(const float4* __restrict__ in,
                                                     uint4* __restrict__ out) {
    int t = blockIdx.x * 256 + threadIdx.x;  // 4096 blocks, 64B read / 32B write each
#pragma unroll
    for (int u = 0; u < 2; u++) {
        float4 a = in[4 * t + 2 * u];
        float4 b = in[4 * t + 2 * u + 1];
        uint4 o;
        o.x = f2bf(a.x) | (f2bf(a.y) << 16);
        o.y = f2bf(a.z) | (f2bf(a.w) << 16);
        o.z = f2bf(b.x) | (f2bf(b.y) << 16);
        o.w = f2bf(b.z) | (f2bf(b.w) << 16);
        out[2 * t + u] = o;
    }
}

// ---- kernel 2: quantize + transpose W[k][n] -> Bt[n][k] bf16 ----------------

__global__ __launch_bounds__(256) void quant_transpose_kernel(const float* __restrict__ W,
                                                              u16* __restrict__ Bt) {
    __shared__ u16 tile[32][33];  // +1 pad: no bank conflicts
    const int KN = 1024;
    int tx = threadIdx.x;  // 0..31
    int ty = threadIdx.y;  // 0..7
    int k0 = blockIdx.y * 32;
    int n0 = blockIdx.x * 32;
#pragma unroll
    for (int i = 0; i < 4; i++) {
        int kl = ty + i * 8;
        float x = W[(k0 + kl) * KN + n0 + tx];
        tile[kl][tx] = (u16)f2bf(quant_w(x));
    }
    __syncthreads();
#pragma unroll
    for (int i = 0; i < 4; i++) {
        int nl = ty + i * 8;
        Bt[(n0 + nl) * KN + k0 + tx] = tile[tx][nl];
    }
}

// ---- kernel 3: 256x256 2-region pipelined GEMM  C = A(bf16) * Bt^T ----------
// 512 thr = 8 waves (2M x 4N), per-wave 128x64 out, BK=64, LDS 128 KB (2 dbuf).
// R5 (4 regions, drains) = 41.6us @ MfmaUtil 29%: ~250cyc/barrier x4 + pipe
// serialization. R7: 2 regions/tile, UNEVEN clusters (16/48 MFMA) chosen so the
// register peak stays 96 frag VGPRs (an even 32/32 split needs 128 -> spills):
//
//  H0(t): M3(t-1)=af1xbf1 (16) || read af0,bf0(t) (12) || DMA Ahi,Bu1(t+1)
//         ; vmcnt(8) lgkm bar
//  H1(t): af0xbf0 + af1xbf0 + af0xbf1 (48; af1,bf1 read in-region, fed by
//         compiler's counted lgkm) || read af1,bf1(t) (12) || DMA Alo,Bu0(t+2)
//         ; vmcnt(8) lgkm bar
//
// DMA units (2 gloads each; per-wave rows stay linear, no 32-row boundary
// crossed within a wave's 8 rows):
//   Alo = A slot rows 0-63 (af0 rows), Ahi = rows 64-127 (af1 rows)
//   Bu0 = B slot rows {0-31,64-95} (bf0 rows), Bu1 = {32-63,96-127} (bf1 rows)
// WAR: every DMA lands >=1 lgkm-drained barrier after its rows' last reader;
//   same-region DMA targets rows disjoint from that region's reads:
//   Ahi/Bu1(t+1)@H0(t) -> buf b^1, rows last read @H1(t-1) (drained) ;
//   Alo/Bu0(t+2)@H1(t) -> buf b, rows last read @H0(t) (drained), disjoint
//   from H1's af1/bf1 read rows.
// RAW (4 ops/region, in-order): steady vmcnt(8) at BOTH region ends drains
//   exactly the 4 loads needed next region, leaves 8 in flight (2-region
//   arrival window). Prologue {Alo0,Bu00,Ahi0,Bu10,Alo1,Bu01} vmcnt(8).
//   Tail: H1(14) vmcnt(4), H0(15) vmcnt(0).
// Per-acc MFMA order identical to R5 -> bitwise-equal C.

__global__ __launch_bounds__(512, 2) void gemm_2region_kernel(const u16* __restrict__ A,
                                                              const u16* __restrict__ Bt,
                                                              float* __restrict__ C) {
    const int K = 1024;
    const int N = 1024;

    __shared__ alignas(16) u16 As[2 * 2 * 128 * 64];  // 64 KB
    __shared__ alignas(16) u16 Bs[2 * 2 * 128 * 64];  // 64 KB

    const int tid = threadIdx.x;
    const int lane = tid & 63;
    const int wid = tid >> 6;
    const int wm = wid >> 2;      // M half (128 rows)
    const int wn = wid & 3;       // N quarter (64 cols)
    const int frow = lane & 15;
    const int fkc = lane >> 4;
    const int rsw = frow & 7;
    const int mbase = blockIdx.x * 256;
    const int nbase = blockIdx.y * 256;

    const int sr = tid >> 3;              // 0..63 staging row
    const int gc = (tid & 7) ^ (sr & 7);  // swizzled global k-chunk (row&7 == sr&7 for all units)
    const int brow0 = ((sr >> 5) << 6) | (sr & 31);  // B u-remap: rows {0-31,64-95}

    floatx4 acc[8][4] = {};
    bf16x8 af0[4][2], af1[4][2], bf0[2][2], bf1[2][2];

    // A unit u: rows u*64 + 0..63 of each hf-slot (2 gloads)
    auto astage = [&](int tau, int u) {
        const int row = sr + u * 64;
#pragma unroll
        for (int hf = 0; hf < 2; hf++) {
            const u16* g = &A[(size_t)(mbase + hf * 128 + row) * K + (size_t)tau * 64 + gc * 8];
            u16* dst = &As[(((tau & 1) * 2 + hf) * 8192) + row * 64 + (tid & 7) * 8];
            gload_lds16(g, dst);
        }
    };
    // B unit u: rows brow0 + u*32 ({0-31,64-95} or {32-63,96-127}) of each hf-slot
    auto bstage = [&](int tau, int u) {
        const int row = brow0 + u * 32;
#pragma unroll
        for (int hf = 0; hf < 2; hf++) {
            const u16* g = &Bt[(size_t)(nbase + hf * 128 + row) * K + (size_t)tau * 64 + gc * 8];
            u16* dst = &Bs[(((tau & 1) * 2 + hf) * 8192) + row * 64 + (tid & 7) * 8];
            gload_lds16(g, dst);
        }
    };

#define LGKM0() asm volatile("s_waitcnt lgkmcnt(0)" ::: "memory")
#define VMC(n)  asm volatile("s_waitcnt vmcnt(" #n ")" ::: "memory")
#define BAR()                          \
    __builtin_amdgcn_sched_barrier(0); \
    __builtin_amdgcn_s_barrier();      \
    __builtin_amdgcn_sched_barrier(0)

#define READ_AF0(b)                                                                  \
    _Pragma("unroll") for (int mf = 0; mf < 4; mf++)                                 \
        _Pragma("unroll") for (int s = 0; s < 2; s++)                                \
            af0[mf][s] = *(const bf16x8*)&As[(((b)*2 + wm) * 128 + mf * 16 + frow) * 64 + \
                                             (((s * 4 + fkc) ^ rsw) * 8)]
#define READ_AF1(b)                                                                  \
    _Pragma("unroll") for (int mf = 0; mf < 4; mf++)                                 \
        _Pragma("unroll") for (int s = 0; s < 2; s++)                                \
            af1[mf][s] = *(const bf16x8*)&As[(((b)*2 + wm) * 128 + 64 + mf * 16 + frow) * 64 + \
                                             (((s * 4 + fkc) ^ rsw) * 8)]
#define READ_BF0(b)                                                                  \
    _Pragma("unroll") for (int nf = 0; nf < 2; nf++)                                 \
        _Pragma("unroll") for (int s = 0; s < 2; s++)                                \
            bf0[nf][s] = *(const bf16x8*)&Bs[(((b)*2 + (wn >> 1)) * 128 + (wn & 1) * 64 + nf * 16 + frow) * 64 + \
                                             (((s * 4 + fkc) ^ rsw) * 8)]
#define READ_BF1(b)                                                                  \
    _Pragma("unroll") for (int nf = 0; nf < 2; nf++)                                 \
        _Pragma("unroll") for (int s = 0; s < 2; s++)                                \
            bf1[nf][s] = *(const bf16x8*)&Bs[(((b)*2 + (wn >> 1)) * 128 + (wn & 1) * 64 + 32 + nf * 16 + frow) * 64 + \
                                             (((s * 4 + fkc) ^ rsw) * 8)]
#define MFMA_CL(af, bf, mo, no)                                                      \
    __builtin_amdgcn_s_setprio(1);                                                   \
    _Pragma("unroll") for (int mf = 0; mf < 4; mf++)                                 \
        _Pragma("unroll") for (int nf = 0; nf < 2; nf++)                             \
            _Pragma("unroll") for (int s = 0; s < 2; s++)                            \
                acc[(mo) + mf][(no) + nf] = __builtin_amdgcn_mfma_f32_16x16x32_bf16( \
                    af[mf][s], bf[nf][s], acc[(mo) + mf][(no) + nf], 0, 0, 0);       \
    __builtin_amdgcn_s_setprio(0)

    // ---- prologue: {Alo,Bu0}(0), {Ahi,Bu1}(0), {Alo,Bu0}(1) = 12 ops ----
    astage(0, 0); bstage(0, 0);
    astage(0, 1); bstage(0, 1);
    astage(1, 0); bstage(1, 0);
    VMC(8);   // lands Alo(0),Bu0(0); 8 in flight
    BAR();

    for (int t = 0; t < 16; t++) {
        const int b = t & 1;

        // ---- H0: M3(t-1) || read af0,bf0(t) || DMA Ahi,Bu1(t+1) ----
        if (t > 0) { MFMA_CL(af1, bf1, 4, 2); }
        READ_AF0(b);
        READ_BF0(b);
        if (t <= 14) {
            astage(t + 1, 1); bstage(t + 1, 1);
            VMC(8);   // lands Ahi(t),Bu1(t) for H1's reads
        } else {
            VMC(0);   // t=15: land Ahi(15),Bu1(15)
        }
        LGKM0();
        BAR();

        // ---- H1: 48 MFMA || read af1,bf1(t) || DMA Alo,Bu0(t+2) ----
        READ_AF1(b);
        READ_BF1(b);
        MFMA_CL(af0, bf0, 0, 0);
        MFMA_CL(af1, bf0, 4, 0);
        MFMA_CL(af0, bf1, 0, 2);
        if (t <= 13) {
            astage(t + 2, 0); bstage(t + 2, 0);
            VMC(8);   // lands Alo(t+1),Bu0(t+1) for next H0's reads
        } else if (t == 14) {
            VMC(4);   // lands Alo(15),Bu0(15)
        }
        LGKM0();
        BAR();
    }

    // ---- epilogue MFMA: M3(15) ----
    MFMA_CL(af1, bf1, 4, 2);

#undef LGKM0
#undef VMC
#undef BAR
#undef READ_AF0
#undef READ_AF1
#undef READ_BF0
#undef READ_BF1
#undef MFMA_CL

    // epilogue: C/D layout col = lane&15, row = (lane>>4)*4 + reg
    const int crow = (lane >> 4) * 4;
    const int ccol = lane & 15;
#pragma unroll
    for (int i = 0; i < 8; i++) {
#pragma unroll
        for (int j = 0; j < 4; j++) {
            float* cp = &C[(size_t)(mbase + wm * 128 + i * 16 + crow) * N +
                           nbase + wn * 64 + j * 16 + ccol];
#pragma unroll
            for (int r = 0; r < 4; r++) cp[r * N] = acc[i][j][r];
        }
    }
}

// ---- launch -----------------------------------------------------------------

extern "C" void kernel_launch(void* const* d_in, const int* in_sizes, int n_in,
                              void* d_out, int out_size, void* d_ws, size_t ws_size,
                              hipStream_t stream) {
    const float* A = (const float*)d_in[0];   // 16384 x 1024 fp32
    const float* W = (const float*)d_in[1];   // 1024 x 1024 fp32
    float* C = (float*)d_out;                 // 16384 x 1024 fp32

    u16* Abf = (u16*)d_ws;                                   // 32 MB bf16 A
    u16* Btq = (u16*)((char*)d_ws + (size_t)33554432);       // 2 MB quantized W^T

    cast_a_kernel<<<4096, 256, 0, stream>>>((const float4*)A, (uint4*)Abf);
    quant_transpose_kernel<<<dim3(32, 32), dim3(32, 8), 0, stream>>>(W, Btq);
    gemm_2region_kernel<<<dim3(64, 4), 512, 0, stream>>>(Abf, Btq, C);
}